// Round 3
// baseline (12512.225 us; speedup 1.0000x reference)
//
#include <hip/hip_runtime.h>
#include <math.h>

#define NV 50000
#define NB 2048
#define NKEEP 65          // K+1
#define RADIUS_F 0.2f

#define FPS_NBLK 32
#define FPS_NTHR 1024

#define ROW_THR 256
#define CAP 5376          // candidate buffer per row (LDS)

// ---------------- no-contract arithmetic helpers ----------------

static __device__ __forceinline__ float sn_nc(float x, float y, float z) {
#pragma clang fp contract(off)
  return (x * x + y * y) + z * z;
}

static __device__ __forceinline__ float d2_nc(float ax, float ay, float az,
                                              float bx, float by, float bz) {
#pragma clang fp contract(off)
  float dx = ax - bx, dy = ay - by, dz = az - bz;
  return (dx * dx + dy * dy) + dz * dz;
}

static __device__ __forceinline__ float tval_nc(float cx, float cy, float cz,
                                                float px, float py, float pz,
                                                float pw) {
#pragma clang fp contract(off)
  float gd = (cx * px + cy * py) + cz * pz;
  return (pw - 2.0f * gd) + pw;
}

// ---------------- helpers ----------------

// key = [gen:16 | d2bits:32 | (0xFFFF - idx):16]; d2>=0 so float bits are
// order-monotone; ties -> smaller idx wins (matches jnp.argmax)
static __device__ __forceinline__ unsigned long long pack_key(int gen, float v, unsigned idx) {
  return ((unsigned long long)(unsigned)gen << 48) |
         ((unsigned long long)__float_as_uint(v) << 16) |
         (unsigned long long)(0xFFFFu - idx);
}

static __device__ __forceinline__ unsigned long long wave_max(unsigned long long k) {
#pragma unroll
  for (int m = 1; m < 64; m <<= 1) {
    unsigned long long o = __shfl_xor(k, m, 64);
    if (o > k) k = o;
  }
  return k;
}

#define KEY_NOTREADY 0xFFFF000000000000ull

// ---------------- kernel 0: pack (x,y,z,sn) + init slots ----------------

__global__ void k_init(const float* __restrict__ vtx, float4* __restrict__ pts,
                       int* __restrict__ cidx, unsigned long long* __restrict__ keys) {
  int i = blockIdx.x * blockDim.x + threadIdx.x;
  if (i < NV) {
    float x = vtx[3 * i], y = vtx[3 * i + 1], z = vtx[3 * i + 2];
    pts[i] = make_float4(x, y, z, sn_nc(x, y, z));
  }
  if (i < 2 * FPS_NBLK) keys[i] = KEY_NOTREADY;   // gen 0xFFFF never matches t<2048
  if (i == 0) cidx[0] = 0;
}

// ---------------- kernel 1: FPS (cooperative, single-word sync protocol) ----------------

__global__ __launch_bounds__(FPS_NTHR, 1)
void k_fps(const float4* __restrict__ pts, int* __restrict__ cidx,
           unsigned long long* __restrict__ keys,
           float* __restrict__ xs, float* __restrict__ ys, float* __restrict__ zs) {
  const int tid = threadIdx.x;
  const int bid = blockIdx.x;
  const int lane = tid & 63;
  const int wid = tid >> 6;
  const int g0 = bid * FPS_NTHR + tid;          // < 32768, always valid
  const int g1 = g0 + FPS_NBLK * FPS_NTHR;      // may be >= NV
  const bool l1 = g1 < NV;

  float x0, y0, z0, x1 = 0.f, y1 = 0.f, z1 = 0.f;
  { float4 p = pts[g0]; x0 = p.x; y0 = p.y; z0 = p.z; }
  if (l1) { float4 p = pts[g1]; x1 = p.x; y1 = p.y; z1 = p.z; }

  float m0, m1 = 0.f;
  {
    float4 s = pts[0];
    m0 = d2_nc(x0, y0, z0, s.x, s.y, s.z);
    if (l1) m1 = d2_nc(x1, y1, z1, s.x, s.y, s.z);
  }

  __shared__ unsigned long long s_w[16];
  __shared__ unsigned long long s_bk;
  __shared__ int s_win;
  __shared__ float s_wx, s_wy, s_wz;

  // publish this block's (winner key + winner coords) for step t into parity slot
  auto publish = [&](int t) {
    const int par = t & 1;
    unsigned long long k0 = pack_key(t, m0, (unsigned)g0);
    unsigned long long k = k0;
    unsigned long long k1 = 0ull;
    if (l1) { k1 = pack_key(t, m1, (unsigned)g1); if (k1 > k) k = k1; }
    k = wave_max(k);
    if (lane == 0) s_w[wid] = k;
    __syncthreads();                                   // SYNC_A
    if (tid < 64) {
      unsigned long long kk = (tid < 16) ? s_w[tid] : 0ull;
      kk = wave_max(kk);
      if (tid == 0) s_bk = kk;
    }
    __syncthreads();                                   // SYNC_B
    const unsigned long long kb = s_bk;
    const int slot = par * FPS_NBLK + bid;
    if (k0 == kb) {                                    // owner thread (unique) writes
      __hip_atomic_store(&xs[slot], x0, __ATOMIC_RELAXED, __HIP_MEMORY_SCOPE_AGENT);
      __hip_atomic_store(&ys[slot], y0, __ATOMIC_RELAXED, __HIP_MEMORY_SCOPE_AGENT);
      __hip_atomic_store(&zs[slot], z0, __ATOMIC_RELAXED, __HIP_MEMORY_SCOPE_AGENT);
      __hip_atomic_store(&keys[slot], kb, __ATOMIC_RELEASE, __HIP_MEMORY_SCOPE_AGENT);
    } else if (l1 && k1 == kb) {
      __hip_atomic_store(&xs[slot], x1, __ATOMIC_RELAXED, __HIP_MEMORY_SCOPE_AGENT);
      __hip_atomic_store(&ys[slot], y1, __ATOMIC_RELAXED, __HIP_MEMORY_SCOPE_AGENT);
      __hip_atomic_store(&zs[slot], z1, __ATOMIC_RELAXED, __HIP_MEMORY_SCOPE_AGENT);
      __hip_atomic_store(&keys[slot], kb, __ATOMIC_RELEASE, __HIP_MEMORY_SCOPE_AGENT);
    }
  };

  // wait for all 32 slots of step t (parity par), compute global winner
  auto pollwin = [&](int t) {
    const int par = t & 1;
    if (tid < 64) {
      unsigned long long k = 0ull;
      float wx = 0.f, wy = 0.f, wz = 0.f;
      if (tid < 32) {
        const int slot = par * FPS_NBLK + tid;
        const unsigned want = (unsigned)t;
        for (;;) {
          k = __hip_atomic_load(&keys[slot], __ATOMIC_ACQUIRE, __HIP_MEMORY_SCOPE_AGENT);
          if ((unsigned)(k >> 48) == want) break;
          __builtin_amdgcn_s_sleep(1);
        }
        wx = __hip_atomic_load(&xs[slot], __ATOMIC_RELAXED, __HIP_MEMORY_SCOPE_AGENT);
        wy = __hip_atomic_load(&ys[slot], __ATOMIC_RELAXED, __HIP_MEMORY_SCOPE_AGENT);
        wz = __hip_atomic_load(&zs[slot], __ATOMIC_RELAXED, __HIP_MEMORY_SCOPE_AGENT);
      }
      const unsigned long long kmax = wave_max(k);     // lanes 32..63 hold 0, never win
      const unsigned long long ball = __ballot(k == kmax);
      const int src = __ffsll((long long)ball) - 1;
      wx = __shfl(wx, src, 64);
      wy = __shfl(wy, src, 64);
      wz = __shfl(wz, src, 64);
      if (tid == 0) {
        s_win = (int)(0xFFFFu - (unsigned)(kmax & 0xFFFFull));
        s_wx = wx; s_wy = wy; s_wz = wz;
      }
    }
    __syncthreads();                                   // SYNC_C
  };

  publish(0);
  for (int t = 1; t < NB; ++t) {
    pollwin(t - 1);
    if (bid == 0 && tid == 0) cidx[t] = s_win;
    const float wx = s_wx, wy = s_wy, wz = s_wz;
    m0 = fminf(m0, d2_nc(x0, y0, z0, wx, wy, wz));
    if (l1) m1 = fminf(m1, d2_nc(x1, y1, z1, wx, wy, wz));
    publish(t);
  }
}

// ---------------- kernel 2: per-centroid select + MLP + aggregate + global ----------------

__global__ __launch_bounds__(ROW_THR, 3)
void k_row(const float4* __restrict__ pts, const int* __restrict__ cidx,
           const float* __restrict__ W1, const float* __restrict__ b1,
           const float* __restrict__ W2, const float* __restrict__ b2,
           const float* __restrict__ Wg, const float* __restrict__ bg,
           float* __restrict__ out) {
  const int tid = threadIdx.x;
  const int row = blockIdx.x;

  __shared__ unsigned hist[1024];
  __shared__ unsigned psum[ROW_THR];
  __shared__ float cd[CAP];
  __shared__ int cidb[CAP];
  __shared__ int vlist[NKEEP];
  __shared__ float s_h[4][64];
  __shared__ float s_mred[4][64];
  __shared__ float s_agg[64];
  __shared__ int s_validn, s_k, s_mode, s_ncand, s_cntle;

  const float4 c4 = pts[cidx[row]];

  for (int i = tid; i < 1024; i += ROW_THR) hist[i] = 0u;
  if (tid == 0) { s_ncand = 0; s_cntle = 0; }
  __syncthreads();

  // pass 1: histogram of d over [0, 0.2]
  for (int j = tid; j < NV; j += ROW_THR) {
    const float4 p = pts[j];
    const float t = tval_nc(c4.x, c4.y, c4.z, p.x, p.y, p.z, p.w);
    const float at = fabsf(t);
    if (at <= 0.0402f) {                 // conservative prefilter: d > 0.2004 otherwise
      const float d = sqrtf(at);
      if (d <= RADIUS_F) {
        atomicAdd(&s_cntle, 1);
        int b = (int)(d * 5120.0f); if (b > 1023) b = 1023;
        atomicAdd(&hist[b], 1u);
      }
    }
  }
  __syncthreads();

  {
    const int base = tid * 4;
    psum[tid] = hist[base] + hist[base + 1] + hist[base + 2] + hist[base + 3];
  }
  __syncthreads();
  if (tid == 0) {
    if (s_cntle <= NKEEP) {
      s_mode = 0; s_k = 1023;            // all in-radius points are valid
    } else {
      int cum = 0, kk = 1023;
      for (int i = 0; i < ROW_THR; ++i) {
        const int nc = cum + (int)psum[i];
        if (nc >= NKEEP) {
          int c2 = cum;
          for (int b = 0; b < 4; ++b) {
            c2 += (int)hist[i * 4 + b];
            if (c2 >= NKEEP) { kk = i * 4 + b; break; }
          }
          break;
        }
        cum = nc;
      }
      s_mode = 1; s_k = kk;
    }
  }
  __syncthreads();
  const int mode = s_mode, kbin = s_k;

  // pass 2: compact candidates
  for (int j = tid; j < NV; j += ROW_THR) {
    const float4 p = pts[j];
    const float t = tval_nc(c4.x, c4.y, c4.z, p.x, p.y, p.z, p.w);
    const float at = fabsf(t);
    if (at <= 0.0402f) {
      const float d = sqrtf(at);
      if (d <= RADIUS_F) {
        int b = (int)(d * 5120.0f); if (b > 1023) b = 1023;
        if (mode == 0 || b <= kbin) {
          const int pos = atomicAdd(&s_ncand, 1);
          if (pos < CAP) { cd[pos] = d; cidb[pos] = j; }
        }
      }
    }
  }
  __syncthreads();
  int n = s_ncand; if (n > CAP) n = CAP;

  if (mode == 0) {
    if (tid < n) vlist[tid] = cidb[tid];       // n <= 65, all valid (max-agg is order-free)
    if (tid == 0) s_validn = n;
  } else {
    // exact 65 smallest by (d, idx) lexicographic (matches lax.top_k tie-break)
    for (int c = tid; c < n; c += ROW_THR) {
      const float dc = cd[c]; const int ic = cidb[c];
      int r = 0;
      for (int j2 = 0; j2 < n; ++j2) {
        const float dj = cd[j2]; const int ij = cidb[j2];
        r += (int)((dj < dc) | ((dj == dc) & (ij < ic)));
      }
      if (r < NKEEP) vlist[r] = ic;
    }
    if (tid == 0) s_validn = NKEEP;
  }
  __syncthreads();
  const int nvld = s_validn;

  // MLP: 4 neighbor-groups x 64 channels
  const int ch = tid & 63, grp = tid >> 6;
  float amax = -INFINITY;
  for (int base = 0; base < nvld; base += 4) {
    const int slot = base + grp;
    if (slot < nvld) {
      const int j = vlist[slot];
      const float4 p = pts[j];
      const float f3 = p.x - c4.x, f4 = p.y - c4.y, f5 = p.z - c4.z;
      float hs = p.x * W1[ch] + p.y * W1[64 + ch] + p.z * W1[128 + ch]
               + f3 * W1[192 + ch] + f4 * W1[256 + ch] + f5 * W1[320 + ch];
      hs += b1[ch];
      s_h[grp][ch] = fmaxf(hs, 0.f);
    }
    __syncthreads();
    if (slot < nvld) {
      float acc = 0.f;
#pragma unroll 8
      for (int k2 = 0; k2 < 64; ++k2) acc += s_h[grp][k2] * W2[k2 * 64 + ch];
      acc += b2[ch];
      amax = fmaxf(amax, acc);
    }
    __syncthreads();
  }
  s_mred[grp][ch] = amax;
  __syncthreads();
  if (tid < 64) {
    s_agg[tid] = fmaxf(fmaxf(s_mred[0][tid], s_mred[1][tid]),
                       fmaxf(s_mred[2][tid], s_mred[3][tid]));
  }
  __syncthreads();
  if (tid < 128) {
    float acc = 0.f;
#pragma unroll 8
    for (int k2 = 0; k2 < 64; ++k2) acc += s_agg[k2] * Wg[k2 * 128 + tid];
    out[row * 128 + tid] = acc + bg[tid];
  }
}

// ---------------- launch ----------------

extern "C" void kernel_launch(void* const* d_in, const int* in_sizes, int n_in,
                              void* d_out, int out_size, void* d_ws, size_t ws_size,
                              hipStream_t stream) {
  const float* vtx = (const float*)d_in[0];
  const float* W1  = (const float*)d_in[1];
  const float* b1  = (const float*)d_in[2];
  const float* W2  = (const float*)d_in[3];
  const float* b2  = (const float*)d_in[4];
  const float* Wg  = (const float*)d_in[5];
  const float* bg  = (const float*)d_in[6];
  float* out = (float*)d_out;

  char* ws = (char*)d_ws;
  float4* pts = (float4*)ws;                                        // 800000 B
  int* cidx = (int*)(ws + 800000);                                  // 8192 B
  unsigned long long* keys = (unsigned long long*)(ws + 808192);    // 2*32*8 = 512 B
  float* xs = (float*)(ws + 808704);                                // 256 B
  float* ys = (float*)(ws + 808960);                                // 256 B
  float* zs = (float*)(ws + 809216);                                // 256 B

  k_init<<<dim3((NV + 255) / 256), dim3(256), 0, stream>>>(vtx, pts, cidx, keys);

  void* args[] = { (void*)&pts, (void*)&cidx, (void*)&keys,
                   (void*)&xs, (void*)&ys, (void*)&zs };
  (void)hipLaunchCooperativeKernel((void*)k_fps, dim3(FPS_NBLK), dim3(FPS_NTHR), args, 0, stream);

  k_row<<<dim3(NB), dim3(ROW_THR), 0, stream>>>(pts, cidx, W1, b1, W2, b2, Wg, bg, out);
}

// Round 5
// 8573.112 us; speedup vs baseline: 1.4595x; 1.4595x over previous
//
#include <hip/hip_runtime.h>
#include <math.h>

#define NV 50000
#define NB 2048
#define NKEEP 65          // K+1
#define RADIUS_F 0.2f

#define FPS_NBLK 8
#define FPS_NTHR 1024
#define PTS_PER 7         // 8*1024*7 = 57344 >= 50000

#define ROW_THR 256
#define CAP 5376          // candidate buffer per row (LDS)

// ---------------- no-contract arithmetic helpers ----------------

static __device__ __forceinline__ float sn_nc(float x, float y, float z) {
#pragma clang fp contract(off)
  return (x * x + y * y) + z * z;
}

static __device__ __forceinline__ float d2_nc(float ax, float ay, float az,
                                              float bx, float by, float bz) {
#pragma clang fp contract(off)
  float dx = ax - bx, dy = ay - by, dz = az - bz;
  return (dx * dx + dy * dy) + dz * dz;
}

static __device__ __forceinline__ float tval_nc(float cx, float cy, float cz,
                                                float px, float py, float pz,
                                                float pw) {
#pragma clang fp contract(off)
  float gd = (cx * px + cy * py) + cz * pz;
  return (pw - 2.0f * gd) + pw;
}

// ---------------- helpers ----------------

// word0 key = [gen:16 | d2bits:32 | (0xFFFF - idx):16]; d2>=0 so float bits are
// order-monotone; ties -> smaller idx wins (matches jnp.argmax)
static __device__ __forceinline__ unsigned long long pack_key(int gen, float v, unsigned idx) {
  return ((unsigned long long)(unsigned)gen << 48) |
         ((unsigned long long)__float_as_uint(v) << 16) |
         (unsigned long long)(0xFFFFu - idx);
}

static __device__ __forceinline__ unsigned long long wave_max(unsigned long long k) {
#pragma unroll
  for (int m = 1; m < 64; m <<= 1) {
    unsigned long long o = __shfl_xor(k, m, 64);
    if (o > k) k = o;
  }
  return k;
}

#define KEY_NOTREADY 0xFFFF000000000000ull

// ---------------- kernel 0: pack (x,y,z,sn) + init slots ----------------

__global__ void k_init(const float* __restrict__ vtx, float4* __restrict__ pts,
                       int* __restrict__ cidx, unsigned long long* __restrict__ slots) {
  int i = blockIdx.x * blockDim.x + threadIdx.x;
  if (i < NV) {
    float x = vtx[3 * i], y = vtx[3 * i + 1], z = vtx[3 * i + 2];
    pts[i] = make_float4(x, y, z, sn_nc(x, y, z));
  }
  if (i < 2 * FPS_NBLK * 4) slots[i] = KEY_NOTREADY;   // gen fields never match t<2048
  if (i == 0) cidx[0] = 0;
}

// ---------------- kernel 1: FPS (cooperative, self-validating slot words) ----------------

__global__ __launch_bounds__(FPS_NTHR, 1)
void k_fps(const float4* __restrict__ pts, int* __restrict__ cidx,
           unsigned long long* __restrict__ slots) {
  const int tid = threadIdx.x;
  const int bid = blockIdx.x;
  const int lane = tid & 63;
  const int wid = tid >> 6;

  // owned points: g = bid*1024 + tid + k*8192, k in [0,7)
  float px[PTS_PER], py[PTS_PER], pz[PTS_PER], m[PTS_PER];
  unsigned gi[PTS_PER];
  bool lv[PTS_PER];
  {
    const float4 s = pts[0];
#pragma unroll
    for (int k = 0; k < PTS_PER; ++k) {
      const int g = bid * FPS_NTHR + tid + k * (FPS_NBLK * FPS_NTHR);
      gi[k] = (unsigned)g;
      lv[k] = g < NV;
      if (lv[k]) {
        const float4 p = pts[g];
        px[k] = p.x; py[k] = p.y; pz[k] = p.z;
        m[k] = d2_nc(p.x, p.y, p.z, s.x, s.y, s.z);
      } else {
        px[k] = 0.f; py[k] = 0.f; pz[k] = 0.f; m[k] = 0.f;  // d2bits=0 never wins
      }
    }
  }

  __shared__ unsigned long long s_w[16];
  __shared__ unsigned long long s_bk;
  __shared__ int s_win;
  __shared__ float s_wx, s_wy, s_wz;

  unsigned long long mykey;   // this thread's packed best (set in publish)
  float bx = 0.f, by = 0.f, bz = 0.f;

  // local argmax + block reduce + owner publish for step t
  auto publish = [&](int t) {
    // per-thread best over owned points (indices increase with k, so strict > keeps smallest idx)
    float bm = m[0]; unsigned bi = gi[0]; bx = px[0]; by = py[0]; bz = pz[0];
#pragma unroll
    for (int k = 1; k < PTS_PER; ++k) {
      if (m[k] > bm) { bm = m[k]; bi = gi[k]; bx = px[k]; by = py[k]; bz = pz[k]; }
    }
    mykey = pack_key(t, bm, bi);
    unsigned long long k = wave_max(mykey);
    if (lane == 0) s_w[wid] = k;
    __syncthreads();                                   // SYNC_A
    if (tid < 64) {
      unsigned long long kk = (tid < 16) ? s_w[tid] : 0ull;
      kk = wave_max(kk);
      if (tid == 0) s_bk = kk;
    }
    __syncthreads();                                   // SYNC_B
    if (mykey == s_bk) {                               // unique owner (key embeds unique idx)
      const int base = ((t & 1) * FPS_NBLK + bid) * 4;
      const unsigned long long g64 = (unsigned long long)(unsigned)t << 32;
      __hip_atomic_store(&slots[base + 0], s_bk, __ATOMIC_RELAXED, __HIP_MEMORY_SCOPE_AGENT);
      __hip_atomic_store(&slots[base + 1], g64 | __float_as_uint(bx), __ATOMIC_RELAXED, __HIP_MEMORY_SCOPE_AGENT);
      __hip_atomic_store(&slots[base + 2], g64 | __float_as_uint(by), __ATOMIC_RELAXED, __HIP_MEMORY_SCOPE_AGENT);
      __hip_atomic_store(&slots[base + 3], g64 | __float_as_uint(bz), __ATOMIC_RELAXED, __HIP_MEMORY_SCOPE_AGENT);
    }
  };

  // wait for all 8 slots x 4 words of step t, compute global winner + coords
  auto pollwin = [&](int t) {
    const int par = t & 1;
    if (tid < 64) {
      unsigned long long v = 0ull;
      if (tid < 32) {
        const int w = tid & 3;                  // word within slot
        const int s = tid >> 2;                 // slot (block)
        unsigned long long* addr = &slots[(par * FPS_NBLK + s) * 4 + w];
        const unsigned want = (unsigned)t;
        for (;;) {
          v = __hip_atomic_load(addr, __ATOMIC_RELAXED, __HIP_MEMORY_SCOPE_AGENT);
          const unsigned g = (w == 0) ? (unsigned)(v >> 48) : (unsigned)(v >> 32);
          if (g == want) break;
          __builtin_amdgcn_s_sleep(1);
        }
      }
      const bool iskey = (tid < 32) && ((tid & 3) == 0);
      const unsigned long long kl = iskey ? v : 0ull;
      const unsigned long long kmax = wave_max(kl);
      const unsigned long long ball = __ballot(iskey && (kl == kmax));
      const int src = __ffsll((long long)ball) - 1;    // lane 4*s of winning slot
      const unsigned xb = (unsigned)__shfl((long long)v, src + 1, 64);
      const unsigned yb = (unsigned)__shfl((long long)v, src + 2, 64);
      const unsigned zb = (unsigned)__shfl((long long)v, src + 3, 64);
      if (tid == 0) {
        s_win = (int)(0xFFFFu - (unsigned)(kmax & 0xFFFFull));
        s_wx = __uint_as_float(xb);
        s_wy = __uint_as_float(yb);
        s_wz = __uint_as_float(zb);
        if (bid == 0) cidx[t + 1] = s_win;             // winner of step t -> centroid t+1
      }
    }
    __syncthreads();                                   // SYNC_C
  };

  publish(0);
  for (int t = 1; t < NB; ++t) {
    pollwin(t - 1);
    const float wx = s_wx, wy = s_wy, wz = s_wz;
#pragma unroll
    for (int k = 0; k < PTS_PER; ++k) {
      if (lv[k]) m[k] = fminf(m[k], d2_nc(px[k], py[k], pz[k], wx, wy, wz));
    }
    publish(t);
  }
}

// ---------------- kernel 2: per-centroid select + MLP + aggregate + global ----------------

__global__ __launch_bounds__(ROW_THR, 3)
void k_row(const float4* __restrict__ pts, const int* __restrict__ cidx,
           const float* __restrict__ W1, const float* __restrict__ b1,
           const float* __restrict__ W2, const float* __restrict__ b2,
           const float* __restrict__ Wg, const float* __restrict__ bg,
           float* __restrict__ out) {
  const int tid = threadIdx.x;
  const int row = blockIdx.x;

  __shared__ unsigned hist[1024];
  __shared__ unsigned psum[ROW_THR];
  __shared__ float cd[CAP];
  __shared__ int cidb[CAP];
  __shared__ int vlist[NKEEP];
  __shared__ float s_h[4][64];
  __shared__ float s_mred[4][64];
  __shared__ float s_agg[64];
  __shared__ int s_validn, s_k, s_mode, s_ncand, s_cntle;

  const float4 c4 = pts[cidx[row]];

  for (int i = tid; i < 1024; i += ROW_THR) hist[i] = 0u;
  if (tid == 0) { s_ncand = 0; s_cntle = 0; }
  __syncthreads();

  // pass 1: histogram of d over [0, 0.2]
  for (int j = tid; j < NV; j += ROW_THR) {
    const float4 p = pts[j];
    const float t = tval_nc(c4.x, c4.y, c4.z, p.x, p.y, p.z, p.w);
    const float at = fabsf(t);
    if (at <= 0.0402f) {                 // conservative prefilter: d > 0.2004 otherwise
      const float d = sqrtf(at);
      if (d <= RADIUS_F) {
        atomicAdd(&s_cntle, 1);
        int b = (int)(d * 5120.0f); if (b > 1023) b = 1023;
        atomicAdd(&hist[b], 1u);
      }
    }
  }
  __syncthreads();

  {
    const int base = tid * 4;
    psum[tid] = hist[base] + hist[base + 1] + hist[base + 2] + hist[base + 3];
  }
  __syncthreads();
  if (tid == 0) {
    if (s_cntle <= NKEEP) {
      s_mode = 0; s_k = 1023;            // all in-radius points are valid
    } else {
      int cum = 0, kk = 1023;
      for (int i = 0; i < ROW_THR; ++i) {
        const int nc = cum + (int)psum[i];
        if (nc >= NKEEP) {
          int c2 = cum;
          for (int b = 0; b < 4; ++b) {
            c2 += (int)hist[i * 4 + b];
            if (c2 >= NKEEP) { kk = i * 4 + b; break; }
          }
          break;
        }
        cum = nc;
      }
      s_mode = 1; s_k = kk;
    }
  }
  __syncthreads();
  const int mode = s_mode, kbin = s_k;

  // pass 2: compact candidates
  for (int j = tid; j < NV; j += ROW_THR) {
    const float4 p = pts[j];
    const float t = tval_nc(c4.x, c4.y, c4.z, p.x, p.y, p.z, p.w);
    const float at = fabsf(t);
    if (at <= 0.0402f) {
      const float d = sqrtf(at);
      if (d <= RADIUS_F) {
        int b = (int)(d * 5120.0f); if (b > 1023) b = 1023;
        if (mode == 0 || b <= kbin) {
          const int pos = atomicAdd(&s_ncand, 1);
          if (pos < CAP) { cd[pos] = d; cidb[pos] = j; }
        }
      }
    }
  }
  __syncthreads();
  int n = s_ncand; if (n > CAP) n = CAP;

  if (mode == 0) {
    if (tid < n) vlist[tid] = cidb[tid];       // n <= 65, all valid (max-agg is order-free)
    if (tid == 0) s_validn = n;
  } else {
    // exact 65 smallest by (d, idx) lexicographic (matches lax.top_k tie-break)
    for (int c = tid; c < n; c += ROW_THR) {
      const float dc = cd[c]; const int ic = cidb[c];
      int r = 0;
      for (int j2 = 0; j2 < n; ++j2) {
        const float dj = cd[j2]; const int ij = cidb[j2];
        r += (int)((dj < dc) | ((dj == dc) & (ij < ic)));
      }
      if (r < NKEEP) vlist[r] = ic;
    }
    if (tid == 0) s_validn = NKEEP;
  }
  __syncthreads();
  const int nvld = s_validn;

  // MLP: 4 neighbor-groups x 64 channels
  const int ch = tid & 63, grp = tid >> 6;
  float amax = -INFINITY;
  for (int base = 0; base < nvld; base += 4) {
    const int slot = base + grp;
    if (slot < nvld) {
      const int j = vlist[slot];
      const float4 p = pts[j];
      const float f3 = p.x - c4.x, f4 = p.y - c4.y, f5 = p.z - c4.z;
      float hs = p.x * W1[ch] + p.y * W1[64 + ch] + p.z * W1[128 + ch]
               + f3 * W1[192 + ch] + f4 * W1[256 + ch] + f5 * W1[320 + ch];
      hs += b1[ch];
      s_h[grp][ch] = fmaxf(hs, 0.f);
    }
    __syncthreads();
    if (slot < nvld) {
      float acc = 0.f;
#pragma unroll 8
      for (int k2 = 0; k2 < 64; ++k2) acc += s_h[grp][k2] * W2[k2 * 64 + ch];
      acc += b2[ch];
      amax = fmaxf(amax, acc);
    }
    __syncthreads();
  }
  s_mred[grp][ch] = amax;
  __syncthreads();
  if (tid < 64) {
    s_agg[tid] = fmaxf(fmaxf(s_mred[0][tid], s_mred[1][tid]),
                       fmaxf(s_mred[2][tid], s_mred[3][tid]));
  }
  __syncthreads();
  if (tid < 128) {
    float acc = 0.f;
#pragma unroll 8
    for (int k2 = 0; k2 < 64; ++k2) acc += s_agg[k2] * Wg[k2 * 128 + tid];
    out[row * 128 + tid] = acc + bg[tid];
  }
}

// ---------------- launch ----------------

extern "C" void kernel_launch(void* const* d_in, const int* in_sizes, int n_in,
                              void* d_out, int out_size, void* d_ws, size_t ws_size,
                              hipStream_t stream) {
  const float* vtx = (const float*)d_in[0];
  const float* W1  = (const float*)d_in[1];
  const float* b1  = (const float*)d_in[2];
  const float* W2  = (const float*)d_in[3];
  const float* b2  = (const float*)d_in[4];
  const float* Wg  = (const float*)d_in[5];
  const float* bg  = (const float*)d_in[6];
  float* out = (float*)d_out;

  char* ws = (char*)d_ws;
  float4* pts = (float4*)ws;                                        // 800000 B
  int* cidx = (int*)(ws + 800000);                                  // 8192 B
  unsigned long long* slots = (unsigned long long*)(ws + 808192);   // 2*8*4*8 = 512 B

  k_init<<<dim3((NV + 255) / 256), dim3(256), 0, stream>>>(vtx, pts, cidx, slots);

  void* args[] = { (void*)&pts, (void*)&cidx, (void*)&slots };
  (void)hipLaunchCooperativeKernel((void*)k_fps, dim3(FPS_NBLK), dim3(FPS_NTHR), args, 0, stream);

  k_row<<<dim3(NB), dim3(ROW_THR), 0, stream>>>(pts, cidx, W1, b1, W2, b2, Wg, bg, out);
}

// Round 6
// 4756.397 us; speedup vs baseline: 2.6306x; 1.8024x over previous
//
#include <hip/hip_runtime.h>
#include <math.h>

#define NV 50000
#define NB 2048
#define NKEEP 65          // K+1
#define RADIUS_F 0.2f

#define FPS_NBLK 8
#define FPS_NTHR 256
#define PTS_PER 25        // 8*256*25 = 51200 >= 50000
#define FPS_STRIDE (FPS_NBLK * FPS_NTHR)   // 2048

#define ROW_THR 256
#define CAP 5376          // candidate buffer per row (LDS)

// ---------------- no-contract arithmetic helpers ----------------

static __device__ __forceinline__ float sn_nc(float x, float y, float z) {
#pragma clang fp contract(off)
  return (x * x + y * y) + z * z;
}

static __device__ __forceinline__ float d2_nc(float ax, float ay, float az,
                                              float bx, float by, float bz) {
#pragma clang fp contract(off)
  float dx = ax - bx, dy = ay - by, dz = az - bz;
  return (dx * dx + dy * dy) + dz * dz;
}

static __device__ __forceinline__ float tval_nc(float cx, float cy, float cz,
                                                float px, float py, float pz,
                                                float pw) {
#pragma clang fp contract(off)
  float gd = (cx * px + cy * py) + cz * pz;
  return (pw - 2.0f * gd) + pw;
}

// ---------------- helpers ----------------

// word0 key = [gen:16 | d2bits:32 | (0xFFFF - idx):16]; d2>=0 so float bits are
// order-monotone; ties -> smaller idx wins (matches jnp.argmax)
static __device__ __forceinline__ unsigned long long pack_key(int gen, float v, unsigned idx) {
  return ((unsigned long long)(unsigned)gen << 48) |
         ((unsigned long long)__float_as_uint(v) << 16) |
         (unsigned long long)(0xFFFFu - idx);
}

static __device__ __forceinline__ unsigned long long wave_max(unsigned long long k) {
#pragma unroll
  for (int m = 1; m < 64; m <<= 1) {
    unsigned long long o = __shfl_xor(k, m, 64);
    if (o > k) k = o;
  }
  return k;
}

#define KEY_NOTREADY 0xFFFF000000000000ull

// ---------------- kernel 0: pack (x,y,z,sn) + init slots ----------------

__global__ void k_init(const float* __restrict__ vtx, float4* __restrict__ pts,
                       int* __restrict__ cidx, unsigned long long* __restrict__ slots) {
  int i = blockIdx.x * blockDim.x + threadIdx.x;
  if (i < NV) {
    float x = vtx[3 * i], y = vtx[3 * i + 1], z = vtx[3 * i + 2];
    pts[i] = make_float4(x, y, z, sn_nc(x, y, z));
  }
  if (i < 2 * FPS_NBLK * 4) slots[i] = KEY_NOTREADY;   // gen fields never match t<2048
  if (i == 0) cidx[0] = 0;
}

// ---------------- kernel 1: FPS (cooperative, lean critical path) ----------------

__global__ __launch_bounds__(FPS_NTHR, 1)
void k_fps(const float4* __restrict__ pts, int* __restrict__ cidx,
           unsigned long long* __restrict__ slots) {
  const int tid = threadIdx.x;
  const int bid = blockIdx.x;
  const int lane = tid & 63;
  const int wid = tid >> 6;
  const int base = bid * FPS_NTHR + tid;

  __shared__ float ldx[FPS_NTHR * PTS_PER];
  __shared__ float ldy[FPS_NTHR * PTS_PER];
  __shared__ float ldz[FPS_NTHR * PTS_PER];
  __shared__ unsigned long long s_w[4];
  __shared__ float s_wx, s_wy, s_wz;

  // owned points in registers (static indexing only); coords mirrored in LDS
  // so lane 0 can look up the block winner's coords by index.
  float px[PTS_PER], py[PTS_PER], pz[PTS_PER], m[PTS_PER];
  {
    const float4 s = pts[0];
#pragma unroll
    for (int k = 0; k < PTS_PER; ++k) {
      const int g = base + k * FPS_STRIDE;
      const int gc = (g < NV) ? g : 0;
      const float4 p = pts[gc];
      px[k] = p.x; py[k] = p.y; pz[k] = p.z;
      m[k] = (g < NV) ? d2_nc(p.x, p.y, p.z, s.x, s.y, s.z) : 0.f;  // d2bits=0 never wins
      ldx[tid * PTS_PER + k] = p.x;
      ldy[tid * PTS_PER + k] = p.y;
      ldz[tid * PTS_PER + k] = p.z;
    }
  }
  // LDS coord mirror is read by lane 0 only after SYNC_A of iteration 0.

  for (int t = 0; t < NB - 1; ++t) {
    if (t > 0) {
      const float wx = s_wx, wy = s_wy, wz = s_wz;   // winner of step t-1 (barrier B ordered)
#pragma unroll
      for (int k = 0; k < PTS_PER; ++k)
        m[k] = fminf(m[k], d2_nc(px[k], py[k], pz[k], wx, wy, wz));
    }

    // per-thread argmax; k ascending == idx ascending, strict > keeps smallest idx
    float bm = m[0]; int bk = 0;
#pragma unroll
    for (int k = 1; k < PTS_PER; ++k)
      if (m[k] > bm) { bm = m[k]; bk = k; }
    unsigned long long mk = pack_key(t, bm, (unsigned)(base + bk * FPS_STRIDE));
    mk = wave_max(mk);
    if (lane == 0) s_w[wid] = mk;
    __syncthreads();                                   // SYNC_A

    if (wid == 0) {
      // ---- block-level final reduce (4 entries, 2 shfl levels) ----
      unsigned long long bkk = (lane < 4) ? s_w[lane] : 0ull;
      { unsigned long long o = __shfl_xor(bkk, 1, 64); if (o > bkk) bkk = o;
        o = __shfl_xor(bkk, 2, 64); if (o > bkk) bkk = o; }

      // ---- lane 0 publishes this block's winner (coords from LDS mirror) ----
      if (lane == 0) {
        const unsigned wbi = 0xFFFFu - (unsigned)(bkk & 0xFFFFull);
        const int rel = (int)wbi - bid * FPS_NTHR;     // = otid + ok*FPS_STRIDE
        const int otid = rel & (FPS_STRIDE - 1);
        const int ok = rel >> 11;                      // FPS_STRIDE = 2^11
        const float cx = ldx[otid * PTS_PER + ok];
        const float cy = ldy[otid * PTS_PER + ok];
        const float cz = ldz[otid * PTS_PER + ok];
        const int sb = ((t & 1) * FPS_NBLK + bid) * 4;
        const unsigned long long g64 = (unsigned long long)(unsigned)t << 32;
        __hip_atomic_store(&slots[sb + 0], bkk, __ATOMIC_RELAXED, __HIP_MEMORY_SCOPE_AGENT);
        __hip_atomic_store(&slots[sb + 1], g64 | __float_as_uint(cx), __ATOMIC_RELAXED, __HIP_MEMORY_SCOPE_AGENT);
        __hip_atomic_store(&slots[sb + 2], g64 | __float_as_uint(cy), __ATOMIC_RELAXED, __HIP_MEMORY_SCOPE_AGENT);
        __hip_atomic_store(&slots[sb + 3], g64 | __float_as_uint(cz), __ATOMIC_RELAXED, __HIP_MEMORY_SCOPE_AGENT);
      }

      // ---- poll all 8 slots (4 self-validating words each) ----
      unsigned long long v = 0ull;
      if (lane < 32) {
        const int w = lane & 3;                 // word within slot
        const int s = lane >> 2;                // slot (block)
        unsigned long long* addr = &slots[((t & 1) * FPS_NBLK + s) * 4 + w];
        const unsigned want = (unsigned)t;
        for (;;) {
          v = __hip_atomic_load(addr, __ATOMIC_RELAXED, __HIP_MEMORY_SCOPE_AGENT);
          const unsigned g = (w == 0) ? (unsigned)(v >> 48) : (unsigned)(v >> 32);
          if (g == want) break;
          __builtin_amdgcn_s_sleep(1);
        }
      }
      // winner over the 8 key lanes (lanes 4s): 3 shfl levels stay within key lanes
      const bool iskey = (lane < 32) && ((lane & 3) == 0);
      unsigned long long kl = iskey ? v : 0ull;
      { unsigned long long o = __shfl_xor(kl, 4, 64);  if (o > kl) kl = o;
        o = __shfl_xor(kl, 8, 64);  if (o > kl) kl = o;
        o = __shfl_xor(kl, 16, 64); if (o > kl) kl = o; }
      const unsigned long long ball = __ballot(iskey && (kl != 0ull) && (v == kl));
      const int src = __ffsll((long long)ball) - 1;    // key lane of winning slot
      const unsigned xb = (unsigned)__shfl((long long)v, src + 1, 64);
      const unsigned yb = (unsigned)__shfl((long long)v, src + 2, 64);
      const unsigned zb = (unsigned)__shfl((long long)v, src + 3, 64);
      if (lane == 0) {
        s_wx = __uint_as_float(xb);
        s_wy = __uint_as_float(yb);
        s_wz = __uint_as_float(zb);
        const unsigned long long kmax = __shfl(kl, 0, 64);  // lane 0 already has kmax
        if (bid == 0) cidx[t + 1] = (int)(0xFFFFu - (unsigned)(kmax & 0xFFFFull));
      }
    }
    __syncthreads();                                   // SYNC_B
  }
}

// ---------------- kernel 2: per-centroid select + MLP + aggregate + global ----------------

__global__ __launch_bounds__(ROW_THR, 3)
void k_row(const float4* __restrict__ pts, const int* __restrict__ cidx,
           const float* __restrict__ W1, const float* __restrict__ b1,
           const float* __restrict__ W2, const float* __restrict__ b2,
           const float* __restrict__ Wg, const float* __restrict__ bg,
           float* __restrict__ out) {
  const int tid = threadIdx.x;
  const int row = blockIdx.x;

  __shared__ unsigned hist[1024];
  __shared__ unsigned psum[ROW_THR];
  __shared__ float cd[CAP];
  __shared__ int cidb[CAP];
  __shared__ int vlist[NKEEP];
  __shared__ float s_h[4][64];
  __shared__ float s_mred[4][64];
  __shared__ float s_agg[64];
  __shared__ int s_validn, s_k, s_mode, s_ncand, s_cntle;

  const float4 c4 = pts[cidx[row]];

  for (int i = tid; i < 1024; i += ROW_THR) hist[i] = 0u;
  if (tid == 0) { s_ncand = 0; s_cntle = 0; }
  __syncthreads();

  // pass 1: histogram of d over [0, 0.2]
  for (int j = tid; j < NV; j += ROW_THR) {
    const float4 p = pts[j];
    const float t = tval_nc(c4.x, c4.y, c4.z, p.x, p.y, p.z, p.w);
    const float at = fabsf(t);
    if (at <= 0.0402f) {                 // conservative prefilter: d > 0.2004 otherwise
      const float d = sqrtf(at);
      if (d <= RADIUS_F) {
        atomicAdd(&s_cntle, 1);
        int b = (int)(d * 5120.0f); if (b > 1023) b = 1023;
        atomicAdd(&hist[b], 1u);
      }
    }
  }
  __syncthreads();

  {
    const int base = tid * 4;
    psum[tid] = hist[base] + hist[base + 1] + hist[base + 2] + hist[base + 3];
  }
  __syncthreads();
  if (tid == 0) {
    if (s_cntle <= NKEEP) {
      s_mode = 0; s_k = 1023;            // all in-radius points are valid
    } else {
      int cum = 0, kk = 1023;
      for (int i = 0; i < ROW_THR; ++i) {
        const int nc = cum + (int)psum[i];
        if (nc >= NKEEP) {
          int c2 = cum;
          for (int b = 0; b < 4; ++b) {
            c2 += (int)hist[i * 4 + b];
            if (c2 >= NKEEP) { kk = i * 4 + b; break; }
          }
          break;
        }
        cum = nc;
      }
      s_mode = 1; s_k = kk;
    }
  }
  __syncthreads();
  const int mode = s_mode, kbin = s_k;

  // pass 2: compact candidates
  for (int j = tid; j < NV; j += ROW_THR) {
    const float4 p = pts[j];
    const float t = tval_nc(c4.x, c4.y, c4.z, p.x, p.y, p.z, p.w);
    const float at = fabsf(t);
    if (at <= 0.0402f) {
      const float d = sqrtf(at);
      if (d <= RADIUS_F) {
        int b = (int)(d * 5120.0f); if (b > 1023) b = 1023;
        if (mode == 0 || b <= kbin) {
          const int pos = atomicAdd(&s_ncand, 1);
          if (pos < CAP) { cd[pos] = d; cidb[pos] = j; }
        }
      }
    }
  }
  __syncthreads();
  int n = s_ncand; if (n > CAP) n = CAP;

  if (mode == 0) {
    if (tid < n) vlist[tid] = cidb[tid];       // n <= 65, all valid (max-agg is order-free)
    if (tid == 0) s_validn = n;
  } else {
    // exact 65 smallest by (d, idx) lexicographic (matches lax.top_k tie-break)
    for (int c = tid; c < n; c += ROW_THR) {
      const float dc = cd[c]; const int ic = cidb[c];
      int r = 0;
      for (int j2 = 0; j2 < n; ++j2) {
        const float dj = cd[j2]; const int ij = cidb[j2];
        r += (int)((dj < dc) | ((dj == dc) & (ij < ic)));
      }
      if (r < NKEEP) vlist[r] = ic;
    }
    if (tid == 0) s_validn = NKEEP;
  }
  __syncthreads();
  const int nvld = s_validn;

  // MLP: 4 neighbor-groups x 64 channels
  const int ch = tid & 63, grp = tid >> 6;
  float amax = -INFINITY;
  for (int base = 0; base < nvld; base += 4) {
    const int slot = base + grp;
    if (slot < nvld) {
      const int j = vlist[slot];
      const float4 p = pts[j];
      const float f3 = p.x - c4.x, f4 = p.y - c4.y, f5 = p.z - c4.z;
      float hs = p.x * W1[ch] + p.y * W1[64 + ch] + p.z * W1[128 + ch]
               + f3 * W1[192 + ch] + f4 * W1[256 + ch] + f5 * W1[320 + ch];
      hs += b1[ch];
      s_h[grp][ch] = fmaxf(hs, 0.f);
    }
    __syncthreads();
    if (slot < nvld) {
      float acc = 0.f;
#pragma unroll 8
      for (int k2 = 0; k2 < 64; ++k2) acc += s_h[grp][k2] * W2[k2 * 64 + ch];
      acc += b2[ch];
      amax = fmaxf(amax, acc);
    }
    __syncthreads();
  }
  s_mred[grp][ch] = amax;
  __syncthreads();
  if (tid < 64) {
    s_agg[tid] = fmaxf(fmaxf(s_mred[0][tid], s_mred[1][tid]),
                       fmaxf(s_mred[2][tid], s_mred[3][tid]));
  }
  __syncthreads();
  if (tid < 128) {
    float acc = 0.f;
#pragma unroll 8
    for (int k2 = 0; k2 < 64; ++k2) acc += s_agg[k2] * Wg[k2 * 128 + tid];
    out[row * 128 + tid] = acc + bg[tid];
  }
}

// ---------------- launch ----------------

extern "C" void kernel_launch(void* const* d_in, const int* in_sizes, int n_in,
                              void* d_out, int out_size, void* d_ws, size_t ws_size,
                              hipStream_t stream) {
  const float* vtx = (const float*)d_in[0];
  const float* W1  = (const float*)d_in[1];
  const float* b1  = (const float*)d_in[2];
  const float* W2  = (const float*)d_in[3];
  const float* b2  = (const float*)d_in[4];
  const float* Wg  = (const float*)d_in[5];
  const float* bg  = (const float*)d_in[6];
  float* out = (float*)d_out;

  char* ws = (char*)d_ws;
  float4* pts = (float4*)ws;                                        // 800000 B
  int* cidx = (int*)(ws + 800000);                                  // 8192 B
  unsigned long long* slots = (unsigned long long*)(ws + 808192);   // 2*8*4*8 = 512 B

  k_init<<<dim3((NV + 255) / 256), dim3(256), 0, stream>>>(vtx, pts, cidx, slots);

  void* args[] = { (void*)&pts, (void*)&cidx, (void*)&slots };
  (void)hipLaunchCooperativeKernel((void*)k_fps, dim3(FPS_NBLK), dim3(FPS_NTHR), args, 0, stream);

  k_row<<<dim3(NB), dim3(ROW_THR), 0, stream>>>(pts, cidx, W1, b1, W2, b2, Wg, bg, out);
}